// Round 4
// baseline (3985.558 us; speedup 1.0000x reference)
//
#include <hip/hip_runtime.h>
#include <hip/hip_bf16.h>

// ---------------------------------------------------------------------------
// RecurrentAutoencoder on MI355X (gfx950).
// Stage A: LSTM e1  (B=4096, T=140, in=1,  hid=128)  -> h1[4096][128]
// Stage B: Up = permuted input-projection (parallel), serial scan T=4096 -> z
// Stage C+D: decoder LSTMs fused, T=140, single workgroup -> out[140]
//
// Round-4 change: raw s_barrier (lgkmcnt-only wait) replaces __syncthreads in
// all step loops. __syncthreads drains vmcnt(0) before s_barrier, putting the
// per-step global prefetch's L3 latency (~500 cyc) on the serial critical
// path. Raw barrier keeps prefetches in flight across barriers.
// ---------------------------------------------------------------------------

__device__ __forceinline__ float sigm(float x) {
  return 1.0f / (1.0f + __expf(-x));
}
__device__ __forceinline__ float tanh_fast(float x) {
  return 1.0f - 2.0f / (__expf(2.0f * x) + 1.0f);
}

// Raw workgroup barrier: waits LDS ops only (lgkmcnt), does NOT drain vmcnt.
// "memory" clobber pins C++-level LDS access ordering around it.
__device__ __forceinline__ void wg_barrier() {
  asm volatile("s_waitcnt lgkmcnt(0)\n\ts_barrier" ::: "memory");
}

// DPP move: returns src value moved per CTRL (row-of-16 scope), VALU pipe.
template <int CTRL>
__device__ __forceinline__ float dppmv(float v) {
  return __int_as_float(__builtin_amdgcn_update_dpp(
      0, __float_as_int(v), CTRL, 0xF, 0xF, true));
}
#define DPP_XOR1   0xB1   // quad_perm [1,0,3,2]
#define DPP_XOR2   0x4E   // quad_perm [2,3,0,1]
#define DPP_ROT1   0x93   // quad_perm [3,0,1,2]: dest q <- (q-1)&3
#define DPP_HMIRR  0x141  // row_half_mirror (lane ^ 7 within 8)
#define DPP_MIRR   0x140  // row_mirror      (lane ^ 15 within 16)

// swizzled LDS column for 128-wide rows: quarter q shifted by 4 floats
__device__ __forceinline__ int swzc(int k) { return k + ((k >> 5) << 2); }

#define A_BB 16

// ---------------------------------------------------------------------------
// Stage A. 512 threads = 8 waves. Thread: u = wave*16 + (lane>>2) in [0,128),
// q = lane&3. Owns gate rows {u,128+u,256+u,384+u}, k in [32q,32q+32), and the
// c-state of unit u for batches [4q,4q+4). 4-stage ring reduce-scatter (DPP
// rotate) puts complete gate sums for those batches in static registers.
// ---------------------------------------------------------------------------
__global__ __launch_bounds__(512, 2) void lstm_e1_kernel(
    const float* __restrict__ x,     // [4096][140]
    const float* __restrict__ Wih,   // [512][1]
    const float* __restrict__ Whh,   // [512][128]
    const float* __restrict__ bih,   // [512]
    const float* __restrict__ bhh,   // [512]
    float* __restrict__ h1_out)      // [4096][128]
{
  const int j    = threadIdx.x;
  const int lane = j & 63;
  const int w    = j >> 6;
  const int u    = w * 16 + (lane >> 2);  // 0..127
  const int q    = lane & 3;
  const int b0   = blockIdx.x * A_BB;

  __shared__ float Hs[2][A_BB][144];  // swizzled columns
  __shared__ float xs[2][A_BB];

  for (int i = j; i < A_BB * 144; i += 512) ((float*)Hs[0])[i] = 0.0f;
  if (j < A_BB) xs[0][j] = x[(b0 + j) * 140];

  float wr[4][32];
#pragma unroll
  for (int g = 0; g < 4; ++g)
#pragma unroll
    for (int k = 0; k < 32; k += 4)
      *(float4*)&wr[g][k] = *(const float4*)&Whh[(g * 128 + u) * 128 + q * 32 + k];

  float wih[4], bs[4];
#pragma unroll
  for (int g = 0; g < 4; ++g) {
    wih[g] = Wih[g * 128 + u];
    bs[g]  = bih[g * 128 + u] + bhh[g * 128 + u];
  }

  float c[4]  = {0.f, 0.f, 0.f, 0.f};
  float hr[4] = {0.f, 0.f, 0.f, 0.f};
  __syncthreads();

  int cur = 0;
  for (int t = 0; t < 140; ++t) {
    const int nxt = cur ^ 1;

    float R[4][4];
#pragma unroll
    for (int g = 0; g < 4; ++g)
#pragma unroll
      for (int i = 0; i < 4; ++i) R[g][i] = 0.0f;

#pragma unroll
    for (int s = 0; s < 4; ++s) {
      if (s) {
#pragma unroll
        for (int g = 0; g < 4; ++g)
#pragma unroll
          for (int i = 0; i < 4; ++i) R[g][i] = dppmv<DPP_ROT1>(R[g][i]);
      }
      const int cch = (q - 1 - s) & 3;  // batch chunk visited this stage
      const float* hbase = &Hs[cur][cch * 4][q * 36];
#pragma unroll
      for (int i = 0; i < 4; ++i) {
        const float* hrow = hbase + i * 144;
#pragma unroll
        for (int kk = 0; kk < 8; ++kk) {
          const float4 hv = *(const float4*)&hrow[kk * 4];
#pragma unroll
          for (int g = 0; g < 4; ++g) {
            R[g][i] = __builtin_fmaf(wr[g][kk * 4 + 0], hv.x, R[g][i]);
            R[g][i] = __builtin_fmaf(wr[g][kk * 4 + 1], hv.y, R[g][i]);
            R[g][i] = __builtin_fmaf(wr[g][kk * 4 + 2], hv.z, R[g][i]);
            R[g][i] = __builtin_fmaf(wr[g][kk * 4 + 3], hv.w, R[g][i]);
          }
        }
      }
    }

    if (j < A_BB && (t + 1) < 140) xs[nxt][j] = x[(b0 + j) * 140 + t + 1];

    const float4 xv = *(const float4*)&xs[cur][q * 4];
    const float xa[4] = {xv.x, xv.y, xv.z, xv.w};
#pragma unroll
    for (int i = 0; i < 4; ++i) {
      const float gi = sigm(R[0][i] + __builtin_fmaf(wih[0], xa[i], bs[0]));
      const float gf = sigm(R[1][i] + __builtin_fmaf(wih[1], xa[i], bs[1]));
      const float gg = tanh_fast(R[2][i] + __builtin_fmaf(wih[2], xa[i], bs[2]));
      const float go = sigm(R[3][i] + __builtin_fmaf(wih[3], xa[i], bs[3]));
      c[i]  = gf * c[i] + gi * gg;
      hr[i] = go * tanh_fast(c[i]);
      Hs[nxt][q * 4 + i][swzc(u)] = hr[i];
    }
    wg_barrier();
    cur = nxt;
  }

#pragma unroll
  for (int i = 0; i < 4; ++i)
    h1_out[(b0 + q * 4 + i) * 128 + u] = hr[i];
}

// ---------------------------------------------------------------------------
// Stage B input projection, PERMUTED output:
// Up[t][u] = float4( pre_i, pre_f, pre_g, pre_o ) for unit u (biases folded).
// ---------------------------------------------------------------------------
__global__ __launch_bounds__(256, 1) void u_pre_kernel(
    const float* __restrict__ h1,   // [4096][128]
    const float* __restrict__ Wih,  // [256][128]
    const float* __restrict__ bih,  // [256]
    const float* __restrict__ bhh,  // [256]
    float* __restrict__ Up)         // [4096][64][4]
{
  const int t = blockIdx.x;
  const int j = threadIdx.x;      // gate row j = g*64 + u
  __shared__ float hs[128];
  if (j < 128) hs[j] = h1[t * 128 + j];
  __syncthreads();
  float acc = bih[j] + bhh[j];
#pragma unroll
  for (int k = 0; k < 128; k += 4) {
    const float4 hv = *(const float4*)&hs[k];
    const float4 wv = *(const float4*)&Wih[j * 128 + k];
    acc += wv.x * hv.x + wv.y * hv.y + wv.z * hv.z + wv.w * hv.w;
  }
  Up[t * 256 + (j & 63) * 4 + (j >> 6)] = acc;
}

// ---------------------------------------------------------------------------
// Stage B serial scan. 512 threads = 8 waves. Thread (u = j>>3, o = j&7) owns
// gate rows {u,64+u,128+u,192+u}, k in [8o,8o+8). 8-lane DPP butterfly;
// c,h replicated; ONE raw barrier per step; Up prefetched 2 steps ahead and
// never drained at the barrier.
// ---------------------------------------------------------------------------
__global__ __launch_bounds__(512, 1) void lstm_e2_scan_kernel(
    const float4* __restrict__ Up,  // [4096][64] of (i,f,g,o)
    const float* __restrict__ Whh,  // [256][64]
    float* __restrict__ z_out)      // [64]
{
  const int j = threadIdx.x;
  const int u = j >> 3;   // 0..63
  const int o = j & 7;    // k-octant

  __shared__ float hb[2][64];

  float wr[4][8];
#pragma unroll
  for (int g = 0; g < 4; ++g) {
    *(float4*)&wr[g][0] = *(const float4*)&Whh[(g * 64 + u) * 64 + o * 8];
    *(float4*)&wr[g][4] = *(const float4*)&Whh[(g * 64 + u) * 64 + o * 8 + 4];
  }

  if (j < 64) hb[0][j] = 0.0f;
  float c = 0.0f, h = 0.0f;

  float4 U0 = Up[u];        // t = 0
  float4 U1 = Up[64 + u];   // t = 1
  __syncthreads();

  int cur = 0;
#pragma unroll 1
  for (int t = 0; t < 4096; t += 2) {
#pragma unroll
    for (int half = 0; half < 2; ++half) {
      const int tp = (t + 2 + half < 4096) ? (t + 2 + half) : 4095;
      const float4 Unew = Up[tp * 64 + u];
      const float4 Ucur = half ? U1 : U0;

      const float4 hv0 = *(const float4*)&hb[cur][o * 8];
      const float4 hv1 = *(const float4*)&hb[cur][o * 8 + 4];
      float a0, a1, a2, a3;
      a0 = wr[0][0] * hv0.x; a1 = wr[1][0] * hv0.x; a2 = wr[2][0] * hv0.x; a3 = wr[3][0] * hv0.x;
      a0 = __builtin_fmaf(wr[0][1], hv0.y, a0); a1 = __builtin_fmaf(wr[1][1], hv0.y, a1);
      a2 = __builtin_fmaf(wr[2][1], hv0.y, a2); a3 = __builtin_fmaf(wr[3][1], hv0.y, a3);
      a0 = __builtin_fmaf(wr[0][2], hv0.z, a0); a1 = __builtin_fmaf(wr[1][2], hv0.z, a1);
      a2 = __builtin_fmaf(wr[2][2], hv0.z, a2); a3 = __builtin_fmaf(wr[3][2], hv0.z, a3);
      a0 = __builtin_fmaf(wr[0][3], hv0.w, a0); a1 = __builtin_fmaf(wr[1][3], hv0.w, a1);
      a2 = __builtin_fmaf(wr[2][3], hv0.w, a2); a3 = __builtin_fmaf(wr[3][3], hv0.w, a3);
      a0 = __builtin_fmaf(wr[0][4], hv1.x, a0); a1 = __builtin_fmaf(wr[1][4], hv1.x, a1);
      a2 = __builtin_fmaf(wr[2][4], hv1.x, a2); a3 = __builtin_fmaf(wr[3][4], hv1.x, a3);
      a0 = __builtin_fmaf(wr[0][5], hv1.y, a0); a1 = __builtin_fmaf(wr[1][5], hv1.y, a1);
      a2 = __builtin_fmaf(wr[2][5], hv1.y, a2); a3 = __builtin_fmaf(wr[3][5], hv1.y, a3);
      a0 = __builtin_fmaf(wr[0][6], hv1.z, a0); a1 = __builtin_fmaf(wr[1][6], hv1.z, a1);
      a2 = __builtin_fmaf(wr[2][6], hv1.z, a2); a3 = __builtin_fmaf(wr[3][6], hv1.z, a3);
      a0 = __builtin_fmaf(wr[0][7], hv1.w, a0); a1 = __builtin_fmaf(wr[1][7], hv1.w, a1);
      a2 = __builtin_fmaf(wr[2][7], hv1.w, a2); a3 = __builtin_fmaf(wr[3][7], hv1.w, a3);

      // 8-lane butterfly, pure VALU
      a0 += dppmv<DPP_XOR1>(a0);  a1 += dppmv<DPP_XOR1>(a1);
      a2 += dppmv<DPP_XOR1>(a2);  a3 += dppmv<DPP_XOR1>(a3);
      a0 += dppmv<DPP_XOR2>(a0);  a1 += dppmv<DPP_XOR2>(a1);
      a2 += dppmv<DPP_XOR2>(a2);  a3 += dppmv<DPP_XOR2>(a3);
      a0 += dppmv<DPP_HMIRR>(a0); a1 += dppmv<DPP_HMIRR>(a1);
      a2 += dppmv<DPP_HMIRR>(a2); a3 += dppmv<DPP_HMIRR>(a3);

      const float gi = sigm(a0 + Ucur.x);
      const float gf = sigm(a1 + Ucur.y);
      const float gg = tanh_fast(a2 + Ucur.z);
      const float go = sigm(a3 + Ucur.w);
      c = gf * c + gi * gg;
      h = go * tanh_fast(c);
      if (o == 0) hb[cur ^ 1][u] = h;
      if (half) U1 = Unew; else U0 = Unew;
      wg_barrier();
      cur ^= 1;
    }
  }
  if (o == 0) z_out[u] = h;
}

// ---------------------------------------------------------------------------
// Stage C+D fused decoder. 512 threads; thread (u = j>>2, q = j&3) runs d1
// with DPP quad reduce; wave 0 then runs d2 row-per-gate (DPP butterfly +
// wave-synchronous LDS broadcast, no extra barrier).
// ---------------------------------------------------------------------------
__global__ __launch_bounds__(512, 1) void lstm_dec_kernel(
    const float* __restrict__ z,      // [64]
    const float* __restrict__ Wih1,   // [512][64]
    const float* __restrict__ Whh1,   // [512][128]
    const float* __restrict__ bih1,   // [512]
    const float* __restrict__ bhh1,   // [512]
    const float* __restrict__ Wih2,   // [4][128]
    const float* __restrict__ Whh2,   // [4][1]
    const float* __restrict__ bih2,   // [4]
    const float* __restrict__ bhh2,   // [4]
    float* __restrict__ out)          // [140]
{
  const int j = threadIdx.x;
  const int u = j >> 2;   // 0..127
  const int q = j & 3;

  __shared__ float hb[2][144];  // swizzled columns
  __shared__ float zs[64];
  __shared__ float act4[4];     // d2 gate sums (wave-0 private)

  if (j < 64) zs[j] = z[j];
  if (j < 144) hb[0][j] = 0.0f;
  __syncthreads();

  float wr[4][32];
#pragma unroll
  for (int g = 0; g < 4; ++g)
#pragma unroll
    for (int k = 0; k < 32; k += 4)
      *(float4*)&wr[g][k] = *(const float4*)&Whh1[(g * 128 + u) * 128 + q * 32 + k];

  float pre0[4];
#pragma unroll
  for (int g = 0; g < 4; ++g) {
    float acc = bih1[g * 128 + u] + bhh1[g * 128 + u];
#pragma unroll
    for (int k = 0; k < 64; k += 4) {
      const float4 zv = *(const float4*)&zs[k];
      const float4 wv = *(const float4*)&Wih1[(g * 128 + u) * 64 + k];
      acc += wv.x * zv.x + wv.y * zv.y + wv.z * zv.z + wv.w * zv.w;
    }
    pre0[g] = acc;
  }

  // d2 lane data: wave 0, lane l: gate g2 = l>>4, elems [8*(l&15), +8)
  const int g2  = j >> 4;
  const int i16 = j & 15;
  float w2d[8] = {0,0,0,0,0,0,0,0};
  if (j < 64) {
#pragma unroll
    for (int e = 0; e < 8; ++e) w2d[e] = Wih2[g2 * 128 + i16 * 8 + e];
  }
  // uniform d2 per-gate constants (loop-invariant)
  const float bb2_0 = bih2[0] + bhh2[0], wh2_0 = Whh2[0];
  const float bb2_1 = bih2[1] + bhh2[1], wh2_1 = Whh2[1];
  const float bb2_2 = bih2[2] + bhh2[2], wh2_2 = Whh2[2];
  const float bb2_3 = bih2[3] + bhh2[3], wh2_3 = Whh2[3];

  float c1 = 0.0f;
  float c2 = 0.0f, h2 = 0.0f;

  int cur = 0;
  for (int t = 0; t < 140; ++t) {
    float a0 = 0.f, a1 = 0.f, a2 = 0.f, a3 = 0.f;
#pragma unroll
    for (int kk = 0; kk < 8; ++kk) {
      const float4 hv = *(const float4*)&hb[cur][q * 36 + kk * 4];
      a0 = __builtin_fmaf(wr[0][kk*4+0], hv.x, a0); a0 = __builtin_fmaf(wr[0][kk*4+1], hv.y, a0);
      a0 = __builtin_fmaf(wr[0][kk*4+2], hv.z, a0); a0 = __builtin_fmaf(wr[0][kk*4+3], hv.w, a0);
      a1 = __builtin_fmaf(wr[1][kk*4+0], hv.x, a1); a1 = __builtin_fmaf(wr[1][kk*4+1], hv.y, a1);
      a1 = __builtin_fmaf(wr[1][kk*4+2], hv.z, a1); a1 = __builtin_fmaf(wr[1][kk*4+3], hv.w, a1);
      a2 = __builtin_fmaf(wr[2][kk*4+0], hv.x, a2); a2 = __builtin_fmaf(wr[2][kk*4+1], hv.y, a2);
      a2 = __builtin_fmaf(wr[2][kk*4+2], hv.z, a2); a2 = __builtin_fmaf(wr[2][kk*4+3], hv.w, a2);
      a3 = __builtin_fmaf(wr[3][kk*4+0], hv.x, a3); a3 = __builtin_fmaf(wr[3][kk*4+1], hv.y, a3);
      a3 = __builtin_fmaf(wr[3][kk*4+2], hv.z, a3); a3 = __builtin_fmaf(wr[3][kk*4+3], hv.w, a3);
    }
    a0 += dppmv<DPP_XOR1>(a0); a0 += dppmv<DPP_XOR2>(a0);
    a1 += dppmv<DPP_XOR1>(a1); a1 += dppmv<DPP_XOR2>(a1);
    a2 += dppmv<DPP_XOR1>(a2); a2 += dppmv<DPP_XOR2>(a2);
    a3 += dppmv<DPP_XOR1>(a3); a3 += dppmv<DPP_XOR2>(a3);

    const float gi = sigm(a0 + pre0[0]);
    const float gf = sigm(a1 + pre0[1]);
    const float gg = tanh_fast(a2 + pre0[2]);
    const float go = sigm(a3 + pre0[3]);
    c1 = gf * c1 + gi * gg;
    const float h1v = go * tanh_fast(c1);
    if (q == 0) hb[cur ^ 1][swzc(u)] = h1v;
    wg_barrier();
    cur ^= 1;

    // ---- d2 on wave 0 (wave-synchronous; no extra barrier) -----------------
    if (j < 64) {
      const int kb = i16 * 8;
      const float4 hA = *(const float4*)&hb[cur][swzc(kb)];
      const float4 hB = *(const float4*)&hb[cur][swzc(kb) + 4];
      float p = hA.x * w2d[0];
      p = __builtin_fmaf(hA.y, w2d[1], p);
      p = __builtin_fmaf(hA.z, w2d[2], p);
      p = __builtin_fmaf(hA.w, w2d[3], p);
      p = __builtin_fmaf(hB.x, w2d[4], p);
      p = __builtin_fmaf(hB.y, w2d[5], p);
      p = __builtin_fmaf(hB.z, w2d[6], p);
      p = __builtin_fmaf(hB.w, w2d[7], p);
      p += dppmv<DPP_XOR1>(p);
      p += dppmv<DPP_XOR2>(p);
      p += dppmv<DPP_HMIRR>(p);
      p += dppmv<DPP_MIRR>(p);      // full row-16 sum in every lane
      if (i16 == 0) act4[g2] = p;
      const float4 acts = *(const float4*)&act4[0];
      const float gi2 = sigm(acts.x + bb2_0 + wh2_0 * h2);
      const float gf2 = sigm(acts.y + bb2_1 + wh2_1 * h2);
      const float gg2 = tanh_fast(acts.z + bb2_2 + wh2_2 * h2);
      const float go2 = sigm(acts.w + bb2_3 + wh2_3 * h2);
      c2 = gf2 * c2 + gi2 * gg2;
      h2 = go2 * tanh_fast(c2);
      if (j == 0) out[t] = h2;
    }
  }
}

// ---------------------------------------------------------------------------
extern "C" void kernel_launch(void* const* d_in, const int* in_sizes, int n_in,
                              void* d_out, int out_size, void* d_ws, size_t ws_size,
                              hipStream_t stream) {
  const float* x      = (const float*)d_in[0];
  const float* Wih_e1 = (const float*)d_in[1];
  const float* Whh_e1 = (const float*)d_in[2];
  const float* bih_e1 = (const float*)d_in[3];
  const float* bhh_e1 = (const float*)d_in[4];
  const float* Wih_e2 = (const float*)d_in[5];
  const float* Whh_e2 = (const float*)d_in[6];
  const float* bih_e2 = (const float*)d_in[7];
  const float* bhh_e2 = (const float*)d_in[8];
  const float* Wih_d1 = (const float*)d_in[9];
  const float* Whh_d1 = (const float*)d_in[10];
  const float* bih_d1 = (const float*)d_in[11];
  const float* bhh_d1 = (const float*)d_in[12];
  const float* Wih_d2 = (const float*)d_in[13];
  const float* Whh_d2 = (const float*)d_in[14];
  const float* bih_d2 = (const float*)d_in[15];
  const float* bhh_d2 = (const float*)d_in[16];

  float* out = (float*)d_out;  // 140 floats

  float* h1 = (float*)d_ws;              // 4096*128
  float* Up = h1 + 4096 * 128;           // 4096*256 (permuted: [t][u][gate])
  float* zb = Up + 4096 * 256;           // 64

  lstm_e1_kernel<<<4096 / A_BB, 512, 0, stream>>>(x, Wih_e1, Whh_e1, bih_e1, bhh_e1, h1);
  u_pre_kernel<<<4096, 256, 0, stream>>>(h1, Wih_e2, bih_e2, bhh_e2, Up);
  lstm_e2_scan_kernel<<<1, 512, 0, stream>>>((const float4*)Up, Whh_e2, zb);
  lstm_dec_kernel<<<1, 512, 0, stream>>>(zb, Wih_d1, Whh_d1, bih_d1, bhh_d1,
                                         Wih_d2, Whh_d2, bih_d2, bhh_d2, out);
}

// Round 5
// 3649.021 us; speedup vs baseline: 1.0922x; 1.0922x over previous
//
#include <hip/hip_runtime.h>
#include <hip/hip_bf16.h>

// ---------------------------------------------------------------------------
// RecurrentAutoencoder on MI355X (gfx950).
// Stage A: LSTM e1  (B=4096, T=140, in=1,  hid=128)  -> h1[4096][128]   [pk_fma]
// Stage B: Up = permuted input-projection (parallel) -> scan+dec fused kernel
// Round-5: burner wgs keep clocks up during serial scan; Up chunked into LDS
// (no per-step global ops); decoder fused into scan kernel; v_pk_fma_f32.
// ---------------------------------------------------------------------------

typedef float v2f __attribute__((ext_vector_type(2)));

__device__ __forceinline__ v2f pk_fma(v2f a, v2f b, v2f c) {
  v2f d;
  asm("v_pk_fma_f32 %0, %1, %2, %3" : "=v"(d) : "v"(a), "v"(b), "v"(c));
  return d;
}

__device__ __forceinline__ float sigm(float x) {
  return 1.0f / (1.0f + __expf(-x));
}
__device__ __forceinline__ float tanh_fast(float x) {
  return 1.0f - 2.0f / (__expf(2.0f * x) + 1.0f);
}

// Raw workgroup barrier: waits LDS ops only (lgkmcnt), does NOT drain vmcnt.
__device__ __forceinline__ void wg_barrier() {
  asm volatile("s_waitcnt lgkmcnt(0)\n\ts_barrier" ::: "memory");
}

// DPP move on VALU pipe (~4 cyc) — row-of-16 scope controls.
template <int CTRL>
__device__ __forceinline__ float dppmv(float v) {
  return __int_as_float(__builtin_amdgcn_update_dpp(
      0, __float_as_int(v), CTRL, 0xF, 0xF, true));
}
#define DPP_XOR1   0xB1   // quad_perm [1,0,3,2]
#define DPP_XOR2   0x4E   // quad_perm [2,3,0,1]
#define DPP_ROT1   0x93   // quad_perm [3,0,1,2]: dest q <- (q-1)&3
#define DPP_HMIRR  0x141  // row_half_mirror (lane ^ 7 within 8)
#define DPP_MIRR   0x140  // row_mirror      (lane ^ 15 within 16)

__device__ __forceinline__ int swzc(int k) { return k + ((k >> 5) << 2); }

#define A_BB 16
#define MAGICSTEP 1u

// ---------------------------------------------------------------------------
// Stage A. 512 threads = 8 waves. Thread: u = wave*16 + (lane>>2), q = lane&3.
// 4-stage ring reduce-scatter (DPP rotate); inner product via v_pk_fma_f32.
// ---------------------------------------------------------------------------
__global__ __launch_bounds__(512, 2) void lstm_e1_kernel(
    const float* __restrict__ x,     // [4096][140]
    const float* __restrict__ Wih,   // [512][1]
    const float* __restrict__ Whh,   // [512][128]
    const float* __restrict__ bih,   // [512]
    const float* __restrict__ bhh,   // [512]
    float* __restrict__ h1_out)      // [4096][128]
{
  const int j    = threadIdx.x;
  const int lane = j & 63;
  const int w    = j >> 6;
  const int u    = w * 16 + (lane >> 2);  // 0..127
  const int q    = lane & 3;
  const int b0   = blockIdx.x * A_BB;

  __shared__ float Hs[2][A_BB][144];  // swizzled columns
  __shared__ float xs[2][A_BB];

  for (int i = j; i < A_BB * 144; i += 512) ((float*)Hs[0])[i] = 0.0f;
  if (j < A_BB) xs[0][j] = x[(b0 + j) * 140];

  // weights as packed pairs: wr2[g][p] = Whh[gate row][q*32 + 2p .. +1]
  v2f wr2[4][16];
#pragma unroll
  for (int g = 0; g < 4; ++g)
#pragma unroll
    for (int k = 0; k < 32; k += 4) {
      const float4 t4 = *(const float4*)&Whh[(g * 128 + u) * 128 + q * 32 + k];
      wr2[g][k / 2 + 0].x = t4.x; wr2[g][k / 2 + 0].y = t4.y;
      wr2[g][k / 2 + 1].x = t4.z; wr2[g][k / 2 + 1].y = t4.w;
    }

  float wih[4], bs[4];
#pragma unroll
  for (int g = 0; g < 4; ++g) {
    wih[g] = Wih[g * 128 + u];
    bs[g]  = bih[g * 128 + u] + bhh[g * 128 + u];
  }

  float c[4]  = {0.f, 0.f, 0.f, 0.f};
  float hr[4] = {0.f, 0.f, 0.f, 0.f};
  __syncthreads();

  int cur = 0;
  for (int t = 0; t < 140; ++t) {
    const int nxt = cur ^ 1;

    v2f R2[4][4];
#pragma unroll
    for (int g = 0; g < 4; ++g)
#pragma unroll
      for (int i = 0; i < 4; ++i) { R2[g][i].x = 0.f; R2[g][i].y = 0.f; }

#pragma unroll
    for (int s = 0; s < 4; ++s) {
      if (s) {
#pragma unroll
        for (int g = 0; g < 4; ++g)
#pragma unroll
          for (int i = 0; i < 4; ++i) {
            R2[g][i].x = dppmv<DPP_ROT1>(R2[g][i].x);
            R2[g][i].y = dppmv<DPP_ROT1>(R2[g][i].y);
          }
      }
      const int cch = (q - 1 - s) & 3;  // batch chunk visited this stage
      const float* hbase = &Hs[cur][cch * 4][q * 36];
#pragma unroll
      for (int i = 0; i < 4; ++i) {
        const float* hrow = hbase + i * 144;
#pragma unroll
        for (int kk = 0; kk < 8; ++kk) {
          const float4 hv = *(const float4*)&hrow[kk * 4];
          v2f h01; h01.x = hv.x; h01.y = hv.y;
          v2f h23; h23.x = hv.z; h23.y = hv.w;
#pragma unroll
          for (int g = 0; g < 4; ++g) {
            R2[g][i] = pk_fma(wr2[g][2 * kk + 0], h01, R2[g][i]);
            R2[g][i] = pk_fma(wr2[g][2 * kk + 1], h23, R2[g][i]);
          }
        }
      }
    }

    if (j < A_BB && (t + 1) < 140) xs[nxt][j] = x[(b0 + j) * 140 + t + 1];

    const float4 xv = *(const float4*)&xs[cur][q * 4];
    const float xa[4] = {xv.x, xv.y, xv.z, xv.w};
#pragma unroll
    for (int i = 0; i < 4; ++i) {
      const float gi = sigm(R2[0][i].x + R2[0][i].y + __builtin_fmaf(wih[0], xa[i], bs[0]));
      const float gf = sigm(R2[1][i].x + R2[1][i].y + __builtin_fmaf(wih[1], xa[i], bs[1]));
      const float gg = tanh_fast(R2[2][i].x + R2[2][i].y + __builtin_fmaf(wih[2], xa[i], bs[2]));
      const float go = sigm(R2[3][i].x + R2[3][i].y + __builtin_fmaf(wih[3], xa[i], bs[3]));
      c[i]  = gf * c[i] + gi * gg;
      hr[i] = go * tanh_fast(c[i]);
      Hs[nxt][q * 4 + i][swzc(u)] = hr[i];
    }
    wg_barrier();
    cur = nxt;
  }

#pragma unroll
  for (int i = 0; i < 4; ++i)
    h1_out[(b0 + q * 4 + i) * 128 + u] = hr[i];
}

// ---------------------------------------------------------------------------
// Stage B input projection, PERMUTED: Up[t][u] = (pre_i,pre_f,pre_g,pre_o).
// ---------------------------------------------------------------------------
__global__ __launch_bounds__(256, 1) void u_pre_kernel(
    const float* __restrict__ h1,   // [4096][128]
    const float* __restrict__ Wih,  // [256][128]
    const float* __restrict__ bih,  // [256]
    const float* __restrict__ bhh,  // [256]
    float* __restrict__ Up)         // [4096][64][4]
{
  const int t = blockIdx.x;
  const int j = threadIdx.x;      // gate row j = g*64 + u
  __shared__ float hs[128];
  if (j < 128) hs[j] = h1[t * 128 + j];
  __syncthreads();
  float acc = bih[j] + bhh[j];
#pragma unroll
  for (int k = 0; k < 128; k += 4) {
    const float4 hv = *(const float4*)&hs[k];
    const float4 wv = *(const float4*)&Wih[j * 128 + k];
    acc += wv.x * hv.x + wv.y * hv.y + wv.z * hv.z + wv.w * hv.w;
  }
  Up[t * 256 + (j & 63) * 4 + (j >> 6)] = acc;
}

// ---------------------------------------------------------------------------
// Fused: serial scan (T=4096, hid=64) + decoder (T=140) on workgroup 0.
// Workgroups 1..255 burn VALU until wg0 bumps the generation flag — keeps
// gfxclk boosted during the serial phase (clock-throttle hypothesis test).
// Scan: Up chunked into LDS 8 steps at a time (double-buffered, refilled from
// registers at chunk tails) — zero global ops on the per-step critical path.
// ---------------------------------------------------------------------------
__global__ __launch_bounds__(512, 1) void scan_dec_kernel(
    const float4* __restrict__ Up,   // [4096][64] of (i,f,g,o)
    const float* __restrict__ WhhB,  // [256][64]
    const float* __restrict__ Wih1,  // [512][64]
    const float* __restrict__ Whh1,  // [512][128]
    const float* __restrict__ bih1,  // [512]
    const float* __restrict__ bhh1,  // [512]
    const float* __restrict__ Wih2,  // [4][128]
    const float* __restrict__ Whh2,  // [4][1]
    const float* __restrict__ bih2,  // [4]
    const float* __restrict__ bhh2,  // [4]
    float* __restrict__ out,         // [140]
    unsigned* __restrict__ flag)
{
  __shared__ float4 Uc4[2][8][64];   // 16 KB: double-buffered Up chunks
  __shared__ float hb[2][64];
  __shared__ float zsd[64];
  __shared__ float hd[2][144];
  __shared__ float act4[4];

  const int j = threadIdx.x;

  if (blockIdx.x != 0) {
    // ---- burner: keep the chip's clock domain busy -------------------------
    const unsigned g0 = __hip_atomic_load(flag, __ATOMIC_RELAXED,
                                          __HIP_MEMORY_SCOPE_AGENT);
    float acc = (float)j;
    for (;;) {
#pragma unroll
      for (int i = 0; i < 256; ++i) acc = __builtin_fmaf(acc, 1.0000001f, 1.0f);
      asm volatile("" :: "v"(acc));  // keep live
      if (__hip_atomic_load(flag, __ATOMIC_RELAXED,
                            __HIP_MEMORY_SCOPE_AGENT) != g0) break;
    }
    return;
  }

  // ======================= scan phase (wg 0) ===============================
  const int u  = j >> 3;    // 0..63
  const int o  = j & 7;     // k-octant
  const int so = j >> 6;    // step-offset served by this thread for refills
  const int uu = j & 63;    // unit served by this thread for refills

  v2f wr2[4][4];
#pragma unroll
  for (int g = 0; g < 4; ++g) {
    const float4 a = *(const float4*)&WhhB[(g * 64 + u) * 64 + o * 8];
    const float4 b = *(const float4*)&WhhB[(g * 64 + u) * 64 + o * 8 + 4];
    wr2[g][0].x = a.x; wr2[g][0].y = a.y;
    wr2[g][1].x = a.z; wr2[g][1].y = a.w;
    wr2[g][2].x = b.x; wr2[g][2].y = b.y;
    wr2[g][3].x = b.z; wr2[g][3].y = b.w;
  }

  if (j < 64) hb[0][j] = 0.0f;
  float c = 0.0f, h = 0.0f;

  // prologue: chunk 0 -> buf 0; chunk 1 load left in flight in rN
  float4 r0 = Up[so * 64 + uu];
  Uc4[0][so][uu] = r0;
  float4 rN = Up[(8 + so) * 64 + uu];
  __syncthreads();

#pragma unroll 1
  for (int ck = 0; ck < 512; ++ck) {
    const int buf = ck & 1;
#pragma unroll
    for (int s8 = 0; s8 < 8; ++s8) {
      const float4 Ucur = Uc4[buf][s8][u];   // 8-lane broadcast, conflict-free
      const float4 hv0 = *(const float4*)&hb[buf ^ ((s8 & 1) ? 1 : 0)][0];
      // NOTE: hb parity == step parity; compute index explicitly below.
      (void)hv0;
      const int hparity = (ck * 8 + s8) & 1;
      const float4 ha = *(const float4*)&hb[hparity][o * 8];
      const float4 hbv = *(const float4*)&hb[hparity][o * 8 + 4];
      v2f h0; h0.x = ha.x;  h0.y = ha.y;
      v2f h1; h1.x = ha.z;  h1.y = ha.w;
      v2f h2; h2.x = hbv.x; h2.y = hbv.y;
      v2f h3; h3.x = hbv.z; h3.y = hbv.w;

      v2f A0, A1, A2, A3;
      A0.x = 0.f; A0.y = 0.f; A1 = A0; A2 = A0; A3 = A0;
      A0 = pk_fma(wr2[0][0], h0, A0); A1 = pk_fma(wr2[1][0], h0, A1);
      A2 = pk_fma(wr2[2][0], h0, A2); A3 = pk_fma(wr2[3][0], h0, A3);
      A0 = pk_fma(wr2[0][1], h1, A0); A1 = pk_fma(wr2[1][1], h1, A1);
      A2 = pk_fma(wr2[2][1], h1, A2); A3 = pk_fma(wr2[3][1], h1, A3);
      A0 = pk_fma(wr2[0][2], h2, A0); A1 = pk_fma(wr2[1][2], h2, A1);
      A2 = pk_fma(wr2[2][2], h2, A2); A3 = pk_fma(wr2[3][2], h2, A3);
      A0 = pk_fma(wr2[0][3], h3, A0); A1 = pk_fma(wr2[1][3], h3, A1);
      A2 = pk_fma(wr2[2][3], h3, A2); A3 = pk_fma(wr2[3][3], h3, A3);

      float a0 = A0.x + A0.y, a1 = A1.x + A1.y;
      float a2 = A2.x + A2.y, a3 = A3.x + A3.y;
      a0 += dppmv<DPP_XOR1>(a0);  a1 += dppmv<DPP_XOR1>(a1);
      a2 += dppmv<DPP_XOR1>(a2);  a3 += dppmv<DPP_XOR1>(a3);
      a0 += dppmv<DPP_XOR2>(a0);  a1 += dppmv<DPP_XOR2>(a1);
      a2 += dppmv<DPP_XOR2>(a2);  a3 += dppmv<DPP_XOR2>(a3);
      a0 += dppmv<DPP_HMIRR>(a0); a1 += dppmv<DPP_HMIRR>(a1);
      a2 += dppmv<DPP_HMIRR>(a2); a3 += dppmv<DPP_HMIRR>(a3);

      const float gi = sigm(a0 + Ucur.x);
      const float gf = sigm(a1 + Ucur.y);
      const float gg = tanh_fast(a2 + Ucur.z);
      const float go = sigm(a3 + Ucur.w);
      c = gf * c + gi * gg;
      h = go * tanh_fast(c);
      if (o == 0) hb[hparity ^ 1][u] = h;

      if (s8 == 7 && ck < 511) {
        Uc4[buf ^ 1][so][uu] = rN;               // chunk ck+1 into other buf
        if (ck + 2 < 512) rN = Up[((ck + 2) * 8 + so) * 64 + uu];
      }
      wg_barrier();
    }
  }

  // z -> LDS for the decoder
  if (o == 0) zsd[u] = h;
  __syncthreads();

  // ======================= decoder phase (wg 0) ============================
  const int ud = j >> 2;   // 0..127
  const int q  = j & 3;

  if (j < 144) { hd[0][j] = 0.0f; }
  __syncthreads();

  float wr[4][32];
#pragma unroll
  for (int g = 0; g < 4; ++g)
#pragma unroll
    for (int k = 0; k < 32; k += 4)
      *(float4*)&wr[g][k] = *(const float4*)&Whh1[(g * 128 + ud) * 128 + q * 32 + k];

  float pre0[4];
#pragma unroll
  for (int g = 0; g < 4; ++g) {
    float acc = bih1[g * 128 + ud] + bhh1[g * 128 + ud];
#pragma unroll
    for (int k = 0; k < 64; k += 4) {
      const float4 zv = *(const float4*)&zsd[k];
      const float4 wv = *(const float4*)&Wih1[(g * 128 + ud) * 64 + k];
      acc += wv.x * zv.x + wv.y * zv.y + wv.z * zv.z + wv.w * zv.w;
    }
    pre0[g] = acc;
  }

  const int g2  = j >> 4;
  const int i16 = j & 15;
  float w2d[8] = {0,0,0,0,0,0,0,0};
  if (j < 64) {
#pragma unroll
    for (int e = 0; e < 8; ++e) w2d[e] = Wih2[g2 * 128 + i16 * 8 + e];
  }
  const float bb2_0 = bih2[0] + bhh2[0], wh2_0 = Whh2[0];
  const float bb2_1 = bih2[1] + bhh2[1], wh2_1 = Whh2[1];
  const float bb2_2 = bih2[2] + bhh2[2], wh2_2 = Whh2[2];
  const float bb2_3 = bih2[3] + bhh2[3], wh2_3 = Whh2[3];

  float c1 = 0.0f;
  float c2 = 0.0f, h2 = 0.0f;

  int cur = 0;
  for (int t = 0; t < 140; ++t) {
    float a0 = 0.f, a1 = 0.f, a2 = 0.f, a3 = 0.f;
#pragma unroll
    for (int kk = 0; kk < 8; ++kk) {
      const float4 hv = *(const float4*)&hd[cur][q * 36 + kk * 4];
      a0 = __builtin_fmaf(wr[0][kk*4+0], hv.x, a0); a0 = __builtin_fmaf(wr[0][kk*4+1], hv.y, a0);
      a0 = __builtin_fmaf(wr[0][kk*4+2], hv.z, a0); a0 = __builtin_fmaf(wr[0][kk*4+3], hv.w, a0);
      a1 = __builtin_fmaf(wr[1][kk*4+0], hv.x, a1); a1 = __builtin_fmaf(wr[1][kk*4+1], hv.y, a1);
      a1 = __builtin_fmaf(wr[1][kk*4+2], hv.z, a1); a1 = __builtin_fmaf(wr[1][kk*4+3], hv.w, a1);
      a2 = __builtin_fmaf(wr[2][kk*4+0], hv.x, a2); a2 = __builtin_fmaf(wr[2][kk*4+1], hv.y, a2);
      a2 = __builtin_fmaf(wr[2][kk*4+2], hv.z, a2); a2 = __builtin_fmaf(wr[2][kk*4+3], hv.w, a2);
      a3 = __builtin_fmaf(wr[3][kk*4+0], hv.x, a3); a3 = __builtin_fmaf(wr[3][kk*4+1], hv.y, a3);
      a3 = __builtin_fmaf(wr[3][kk*4+2], hv.z, a3); a3 = __builtin_fmaf(wr[3][kk*4+3], hv.w, a3);
    }
    a0 += dppmv<DPP_XOR1>(a0); a0 += dppmv<DPP_XOR2>(a0);
    a1 += dppmv<DPP_XOR1>(a1); a1 += dppmv<DPP_XOR2>(a1);
    a2 += dppmv<DPP_XOR1>(a2); a2 += dppmv<DPP_XOR2>(a2);
    a3 += dppmv<DPP_XOR1>(a3); a3 += dppmv<DPP_XOR2>(a3);

    const float gi = sigm(a0 + pre0[0]);
    const float gf = sigm(a1 + pre0[1]);
    const float gg = tanh_fast(a2 + pre0[2]);
    const float go = sigm(a3 + pre0[3]);
    c1 = gf * c1 + gi * gg;
    const float h1v = go * tanh_fast(c1);
    if (q == 0) hd[cur ^ 1][swzc(ud)] = h1v;
    wg_barrier();
    cur ^= 1;

    if (j < 64) {
      const int kb = i16 * 8;
      const float4 hA = *(const float4*)&hd[cur][swzc(kb)];
      const float4 hB = *(const float4*)&hd[cur][swzc(kb) + 4];
      float p = hA.x * w2d[0];
      p = __builtin_fmaf(hA.y, w2d[1], p);
      p = __builtin_fmaf(hA.z, w2d[2], p);
      p = __builtin_fmaf(hA.w, w2d[3], p);
      p = __builtin_fmaf(hB.x, w2d[4], p);
      p = __builtin_fmaf(hB.y, w2d[5], p);
      p = __builtin_fmaf(hB.z, w2d[6], p);
      p = __builtin_fmaf(hB.w, w2d[7], p);
      p += dppmv<DPP_XOR1>(p);
      p += dppmv<DPP_XOR2>(p);
      p += dppmv<DPP_HMIRR>(p);
      p += dppmv<DPP_MIRR>(p);
      if (i16 == 0) act4[g2] = p;
      const float4 acts = *(const float4*)&act4[0];  // same-wave, lgkm-ordered
      const float gi2 = sigm(acts.x + bb2_0 + wh2_0 * h2);
      const float gf2 = sigm(acts.y + bb2_1 + wh2_1 * h2);
      const float gg2 = tanh_fast(acts.z + bb2_2 + wh2_2 * h2);
      const float go2 = sigm(acts.w + bb2_3 + wh2_3 * h2);
      c2 = gf2 * c2 + gi2 * gg2;
      h2 = go2 * tanh_fast(c2);
      if (j == 0) out[t] = h2;
    }
  }

  // release burners
  __threadfence();
  if (j == 0)
    (void)__hip_atomic_fetch_add(flag, MAGICSTEP, __ATOMIC_RELEASE,
                                 __HIP_MEMORY_SCOPE_AGENT);
}

// ---------------------------------------------------------------------------
extern "C" void kernel_launch(void* const* d_in, const int* in_sizes, int n_in,
                              void* d_out, int out_size, void* d_ws, size_t ws_size,
                              hipStream_t stream) {
  const float* x      = (const float*)d_in[0];
  const float* Wih_e1 = (const float*)d_in[1];
  const float* Whh_e1 = (const float*)d_in[2];
  const float* bih_e1 = (const float*)d_in[3];
  const float* bhh_e1 = (const float*)d_in[4];
  const float* Wih_e2 = (const float*)d_in[5];
  const float* Whh_e2 = (const float*)d_in[6];
  const float* bih_e2 = (const float*)d_in[7];
  const float* bhh_e2 = (const float*)d_in[8];
  const float* Wih_d1 = (const float*)d_in[9];
  const float* Whh_d1 = (const float*)d_in[10];
  const float* bih_d1 = (const float*)d_in[11];
  const float* bhh_d1 = (const float*)d_in[12];
  const float* Wih_d2 = (const float*)d_in[13];
  const float* Whh_d2 = (const float*)d_in[14];
  const float* bih_d2 = (const float*)d_in[15];
  const float* bhh_d2 = (const float*)d_in[16];

  float* out = (float*)d_out;  // 140 floats

  float* h1 = (float*)d_ws;              // 4096*128
  float* Up = h1 + 4096 * 128;           // 4096*256 (permuted [t][u][gate])
  unsigned* flag = (unsigned*)(Up + 4096 * 256);

  lstm_e1_kernel<<<4096 / A_BB, 512, 0, stream>>>(x, Wih_e1, Whh_e1, bih_e1, bhh_e1, h1);
  u_pre_kernel<<<4096, 256, 0, stream>>>(h1, Wih_e2, bih_e2, bhh_e2, Up);
  scan_dec_kernel<<<256, 512, 0, stream>>>((const float4*)Up, Whh_e2,
                                           Wih_d1, Whh_d1, bih_d1, bhh_d1,
                                           Wih_d2, Whh_d2, bih_d2, bhh_d2,
                                           out, flag);
}